// Round 13
// baseline (507.939 us; speedup 1.0000x reference)
//
#include <hip/hip_runtime.h>
#include <hip/hip_fp16.h>

typedef _Float16 f16;
typedef f16 f16x8 __attribute__((ext_vector_type(8)));
typedef float f32x4 __attribute__((ext_vector_type(4)));

#define NDRUG 100000
#define NCELL 20000
#define EDD   1600000
#define EDC   800000
#define ECD   800000
#define NQ    100000
#define ETOT  (EDD + ECD + EDC)
#define NNODE 220000              // unified dst space: [0,1e5) dd, [1e5,2e5) cd, [2e5,2.2e5) dc

// bucketed build: drug-dst space [0,200000) in 256-node buckets, cell-dst in 64-node buckets
#define NBD 782
#define NBC 313
#define NBTOT (NBD + NBC)          // 1095
#define ECHUNK 4096
#define NBLK ((ETOT + ECHUNK - 1) / ECHUNK)   // 782
#define BCAP 8192                  // fixed global capacity per bucket (mean 4096)
#define LCAP 6144                  // LDS sort capacity per bucket (mean 4096, +32 sigma)
#define CVTG 2048                  // grid-stride blocks for the cvt half of fused dispatch 1
#define GC_PROJ 157                // (NCELL+127)/128
#define GD_PROJ 782                // (NDRUG+127)/128

__device__ inline int bucket_of(int rdst) { return rdst < 200000 ? (rdst >> 8) : NBD + ((rdst - 200000) >> 6); }
__device__ inline int dl_of(int rdst)     { return rdst < 200000 ? (rdst & 255) : ((rdst - 200000) & 63); }

// ---------------- shared-memory layouts ----------------

struct GemmSh { f16 As[128][72]; f16 Ws[128][72]; };     // 36,864 B (+8 pad: 2-way alias free)
struct BktSh {
    int cnt[256]; int off[256]; int seg[256];
    unsigned short lrank[LCAP];
    unsigned srec[LCAP];
};                                                        // 39,936 B
union ShU { GemmSh g; BktSh b; };

// ---------------- GEMM core: C[M,128] = sum_s A_s @ W_s^T + bias ----------------
// 128x128 C-tile, 4 waves x 32 rows, BK=64, fp16 in, fp32 accum.
// MODE 0: fp16 store; MODE 1: relu+fp16 store; MODE 2: relu + dot(m2w) + m2b -> Cf[M].

template<typename AT, int MODE>
__device__ __forceinline__ void gemm_core(
    f16 (*As)[72], f16 (*Ws)[72], int mb,
    const AT* A0, const int* I0, const f16* W0, int K0, int S0,
    const AT* A1, const int* I1, const f16* W1, int K1, int S1,
    const AT* A2, const int* I2, const f16* W2, int K2, int S2,
    const float* bias, f16* Ch, int M,
    const float* m2w, const float* m2b, float* Cf)
{
    const int tid = threadIdx.x;
    const int w  = tid >> 6;
    const int l  = tid & 63;
    const int lc = l & 15;
    const int lq = l >> 4;
    const int sr = tid >> 1;
    const int sk = (tid & 1) * 32;

    f32x4 acc[2][8];
#pragma unroll
    for (int mi = 0; mi < 2; ++mi)
#pragma unroll
        for (int j = 0; j < 8; ++j) acc[mi][j] = (f32x4){0.f, 0.f, 0.f, 0.f};

    const AT*  Aseg[3] = {A0, A1, A2};
    const int* Iseg[3] = {I0, I1, I2};
    const f16* Wseg[3] = {W0, W1, W2};
    const int  Kseg[3] = {K0, K1, K2};
    const int  Sseg[3] = {S0, S1, S2};

    for (int s = 0; s < 3; ++s) {
        const AT* A = Aseg[s];
        if (!A) continue;
        const int* idx = Iseg[s];
        const f16* W = Wseg[s];
        const int K = Kseg[s], S = Sseg[s];

        int m = mb + sr; if (m >= M) m = M - 1;
        const AT*  arow = A + (size_t)(idx ? idx[m] : m) * (size_t)K;
        const f16* wrow = W + (size_t)sr * (size_t)S;

        for (int kt = 0; kt < K; kt += 64) {
            {
                const uint4* ap = (const uint4*)(arow + kt + sk);
                uint4 a0 = ap[0], a1 = ap[1], a2 = ap[2], a3 = ap[3];
                *(uint4*)&As[sr][sk]      = a0;
                *(uint4*)&As[sr][sk + 8]  = a1;
                *(uint4*)&As[sr][sk + 16] = a2;
                *(uint4*)&As[sr][sk + 24] = a3;
            }
            {
                const uint4* wp = (const uint4*)(wrow + kt + sk);
                uint4 w0 = wp[0], w1 = wp[1], w2 = wp[2], w3 = wp[3];
                *(uint4*)&Ws[sr][sk]      = w0;
                *(uint4*)&Ws[sr][sk + 8]  = w1;
                *(uint4*)&Ws[sr][sk + 16] = w2;
                *(uint4*)&Ws[sr][sk + 24] = w3;
            }
            __syncthreads();

#pragma unroll
            for (int ks = 0; ks < 64; ks += 32) {
                f16x8 a0 = *(const f16x8*)&As[32 * w + lc][ks + 8 * lq];
                f16x8 a1 = *(const f16x8*)&As[32 * w + 16 + lc][ks + 8 * lq];
#pragma unroll
                for (int j = 0; j < 8; ++j) {
                    f16x8 b = *(const f16x8*)&Ws[16 * j + lc][ks + 8 * lq];
                    acc[0][j] = __builtin_amdgcn_mfma_f32_16x16x32_f16(a0, b, acc[0][j], 0, 0, 0);
                    acc[1][j] = __builtin_amdgcn_mfma_f32_16x16x32_f16(a1, b, acc[1][j], 0, 0, 0);
                }
            }
            __syncthreads();
        }
    }

    // C/D layout: col = lc + 16j, row = 32w + 16mi + 4*lq + r
    if (MODE == 2) {
        float part[2][4];
#pragma unroll
        for (int mi = 0; mi < 2; ++mi)
#pragma unroll
            for (int r = 0; r < 4; ++r) part[mi][r] = 0.f;
#pragma unroll
        for (int j = 0; j < 8; ++j) {
            float bj = bias[16 * j + lc];
            float wv = m2w[16 * j + lc];
#pragma unroll
            for (int mi = 0; mi < 2; ++mi)
#pragma unroll
                for (int r = 0; r < 4; ++r) {
                    float v = acc[mi][j][r] + bj;
                    v = v > 0.f ? v : 0.f;
                    part[mi][r] = fmaf(v, wv, part[mi][r]);
                }
        }
#pragma unroll
        for (int mi = 0; mi < 2; ++mi)
#pragma unroll
            for (int r = 0; r < 4; ++r) {
                float p = part[mi][r];
#pragma unroll
                for (int o = 1; o < 16; o <<= 1) p += __shfl_xor(p, o, 16);
                if (lc == 0) {
                    int row = mb + 32 * w + 16 * mi + 4 * lq + r;
                    if (row < M) Cf[row] = p + m2b[0];
                }
            }
    } else {
#pragma unroll
        for (int j = 0; j < 8; ++j) {
            float bj = bias[16 * j + lc];
#pragma unroll
            for (int mi = 0; mi < 2; ++mi)
#pragma unroll
                for (int r = 0; r < 4; ++r) {
                    float v = acc[mi][j][r] + bj;
                    if (MODE == 1) v = v > 0.f ? v : 0.f;
                    int row = mb + 32 * w + 16 * mi + 4 * lq + r;
                    if (row < M) Ch[(size_t)row * 128 + 16 * j + lc] = (f16)v;
                }
        }
    }
}

// ---------------- fused dispatch 1: scatter (blocks < NBLK) | fp32->fp16 cvt ----------------

__device__ __forceinline__ int dst_decode(int e,
    const int* __restrict__ ddd, const int* __restrict__ cdd, const int* __restrict__ dcd)
{
    if (e < EDD) return ddd[e];
    if (e < EDD + ECD) return 100000 + cdd[e - EDD];
    return 200000 + dcd[e - EDD - ECD];
}

__device__ __forceinline__ void edge_decode(int e,
    const int* __restrict__ dds, const int* __restrict__ ddd,
    const int* __restrict__ cds, const int* __restrict__ cdd,
    const int* __restrict__ dcs, const int* __restrict__ dcd,
    int& src, int& rdst)
{
    if (e < EDD) { src = dds[e]; rdst = ddd[e]; }
    else if (e < EDD + ECD) { int i = e - EDD; src = cds[i]; rdst = 100000 + cdd[i]; }
    else { int i = e - EDD - ECD; src = dcs[i]; rdst = 200000 + dcd[i]; }
}

__global__ __launch_bounds__(256) void scatter_cvt_k(
    const int* __restrict__ dds, const int* __restrict__ ddd,
    const int* __restrict__ cds, const int* __restrict__ cdd,
    const int* __restrict__ dcs, const int* __restrict__ dcd,
    int* __restrict__ bucket_cur, unsigned* __restrict__ binned,
    const float* __restrict__ xd, f16* __restrict__ xd16,
    const float* __restrict__ xc, f16* __restrict__ xc16)
{
    __shared__ int lh[NBTOT];
    __shared__ int lbase[NBTOT];
    int tid = threadIdx.x;

    if ((int)blockIdx.x < NBLK) {
        for (int i = tid; i < NBTOT; i += 256) lh[i] = 0;
        __syncthreads();

        int base = blockIdx.x * ECHUNK;
        int end = base + ECHUNK; if (end > ETOT) end = ETOT;

        // pass A: bucket counts (dst only), 8-deep ILP
        int e = base + tid;
        for (; e + 1792 < end; e += 2048) {
            int r[8];
#pragma unroll
            for (int u = 0; u < 8; ++u) r[u] = dst_decode(e + 256 * u, ddd, cdd, dcd);
#pragma unroll
            for (int u = 0; u < 8; ++u) atomicAdd(&lh[bucket_of(r[u])], 1);
        }
        for (; e < end; e += 256)
            atomicAdd(&lh[bucket_of(dst_decode(e, ddd, cdd, dcd))], 1);
        __syncthreads();

        for (int i = tid; i < NBTOT; i += 256) {
            int c = lh[i];
            lbase[i] = c ? atomicAdd(&bucket_cur[i], c) : 0;
            lh[i] = 0;
        }
        __syncthreads();

        // pass B: rank + write packed records, 8-deep ILP
        e = base + tid;
        for (; e + 1792 < end; e += 2048) {
            int s[8], r[8], b[8], k[8];
#pragma unroll
            for (int u = 0; u < 8; ++u)
                edge_decode(e + 256 * u, dds, ddd, cds, cdd, dcs, dcd, s[u], r[u]);
#pragma unroll
            for (int u = 0; u < 8; ++u) b[u] = bucket_of(r[u]);
#pragma unroll
            for (int u = 0; u < 8; ++u) k[u] = atomicAdd(&lh[b[u]], 1);
#pragma unroll
            for (int u = 0; u < 8; ++u)
                binned[lbase[b[u]] + k[u]] = ((unsigned)dl_of(r[u]) << 17) | (unsigned)s[u];
        }
        for (; e < end; e += 256) {
            int s, r;
            edge_decode(e, dds, ddd, cds, cdd, dcs, dcd, s, r);
            int b = bucket_of(r);
            int k = atomicAdd(&lh[b], 1);
            binned[lbase[b] + k] = ((unsigned)dl_of(r) << 17) | (unsigned)s;
        }
    } else {
        // coalesced fp32->fp16 conversion, grid-stride over CVTG blocks
        const long TD = (long)NDRUG * 256 / 8;
        const long TC = (long)NCELL * 512 / 8;
        long stride = (long)CVTG * 256;
        for (long t = (long)((int)blockIdx.x - NBLK) * 256 + tid; t < TD + TC; t += stride) {
            const float* src; f16* dst; long p;
            if (t < TD) { src = xd; dst = xd16; p = t; }
            else        { src = xc; dst = xc16; p = t - TD; }
            const float4* sp = (const float4*)(src + p * 8);
            float4 u = sp[0], v = sp[1];
            f16x8 h;
            h[0] = (f16)u.x; h[1] = (f16)u.y; h[2] = (f16)u.z; h[3] = (f16)u.w;
            h[4] = (f16)v.x; h[5] = (f16)v.y; h[6] = (f16)v.z; h[7] = (f16)v.w;
            *(f16x8*)(dst + p * 8) = h;
        }
    }
}

// ---------------- fused dispatch 2: bucket counting-sort (blocks < NBTOT) | proj GEMM ----------------

__global__ __launch_bounds__(256) void bucket_proj_k(
    unsigned* __restrict__ binned, const int* __restrict__ bucket_cur,
    int* __restrict__ rowptr, int* __restrict__ cnt_arr,
    const f16* __restrict__ xc32_16, const f16* __restrict__ wc16, const float* __restrict__ bc, f16* __restrict__ xc_h,
    const f16* __restrict__ xd32_16, const f16* __restrict__ wd16, const float* __restrict__ bd, f16* __restrict__ xd_h)
{
    __shared__ ShU sh;
    int tid = threadIdx.x;

    if ((int)blockIdx.x < NBTOT) {
        int b = blockIdx.x;
        int gbase = b * BCAP;
        int n = bucket_cur[b] - gbase;
        n = n < 0 ? 0 : (n > LCAP ? LCAP : n);

        sh.b.cnt[tid] = 0;
        __syncthreads();
        for (int j = tid; j < n; j += 256) {
            unsigned r = binned[gbase + j];
            sh.b.lrank[j] = (unsigned short)atomicAdd(&sh.b.cnt[r >> 17], 1);
        }
        __syncthreads();
        int c = sh.b.cnt[tid];
        sh.b.seg[tid] = c; __syncthreads();
        for (int o = 1; o < 256; o <<= 1) {
            int v = (tid >= o) ? sh.b.seg[tid - o] : 0;
            __syncthreads();
            sh.b.seg[tid] += v;
            __syncthreads();
        }
        sh.b.off[tid] = sh.b.seg[tid] - c;
        __syncthreads();

        // rowptr + counts for every node in this bucket
        if (b < NBD) {
            int rdst = b * 256 + tid;
            if (rdst < 200000) { rowptr[rdst] = gbase + sh.b.off[tid]; cnt_arr[rdst] = c; }
        } else {
            if (tid < 64) {
                int node = (b - NBD) * 64 + tid;
                if (node < NCELL) { rowptr[200000 + node] = gbase + sh.b.off[tid]; cnt_arr[200000 + node] = c; }
            }
        }

        // node-sorted order in LDS (re-read is L2-hit)
        for (int j = tid; j < n; j += 256) {
            unsigned r = binned[gbase + j];
            int p = sh.b.off[r >> 17] + sh.b.lrank[j];
            sh.b.srec[p] = r & 0x1FFFF;
        }
        __syncthreads();

        // in-place linear write back (block owns this region exclusively)
        for (int p = tid; p < n; p += 256) binned[gbase + p] = sh.b.srec[p];
    } else {
        int bid = (int)blockIdx.x - NBTOT;
        const f16* fn = nullptr; const int* in_ = nullptr;
        if (bid < GC_PROJ) {
            gemm_core<f16, 0>(sh.g.As, sh.g.Ws, bid * 128,
                xc32_16, in_, wc16, 512, 512,
                fn, in_, fn, 0, 0,
                fn, in_, fn, 0, 0,
                bc, xc_h, NCELL, nullptr, nullptr, nullptr);
        } else {
            gemm_core<f16, 0>(sh.g.As, sh.g.Ws, (bid - GC_PROJ) * 128,
                xd32_16, in_, wd16, 256, 256,
                fn, in_, fn, 0, 0,
                fn, in_, fn, 0, 0,
                bd, xd_h, NDRUG, nullptr, nullptr, nullptr);
        }
    }
}

// ---------------- merged mean aggregation over bucket-padded CSR, fp16 rows ----------------

__device__ inline void addv(float* acc, uint4 v)
{
    const __half2* h = (const __half2*)&v;
#pragma unroll
    for (int j = 0; j < 4; ++j) {
        float2 f = __half22float2(h[j]);
        acc[2 * j]     += f.x;
        acc[2 * j + 1] += f.y;
    }
}

__global__ __launch_bounds__(256, 8) void agg_all_k(
    const __half* __restrict__ t_d, const __half* __restrict__ t_c,
    const int* __restrict__ rowptr, const int* __restrict__ cnt_arr,
    const unsigned* __restrict__ packed,
    __half* __restrict__ m_a, __half* __restrict__ m_b, __half* __restrict__ m_c)
{
    int gid = blockIdx.x * 16 + (threadIdx.x >> 4);
    if (gid >= NNODE) return;
    int g = threadIdx.x & 15;

    const __half* tab; __half* out;
    if (gid < 100000)      { tab = t_d; out = m_a + (size_t)gid * 128; }
    else if (gid < 200000) { tab = t_c; out = m_b + (size_t)(gid - 100000) * 128; }
    else                   { tab = t_d; out = m_c + (size_t)(gid - 200000) * 128; }

    int s = rowptr[gid];
    int n = cnt_arr[gid];
    const unsigned* list = packed + s;
    const __half* base = tab + (size_t)g * 8;

    float acc[8];
#pragma unroll
    for (int j = 0; j < 8; ++j) acc[j] = 0.f;

    int i = 0;
    int nb = n - (n % 6);
    if (nb >= 6) {
        // software pipeline: prefetch next 6 list entries while current 6 rows load
        unsigned idx[6];
#pragma unroll
        for (int u = 0; u < 6; ++u) idx[u] = list[u];
        for (i = 6; i < nb; i += 6) {
            unsigned nxt[6];
#pragma unroll
            for (int u = 0; u < 6; ++u) nxt[u] = list[i + u];
            uint4 v[6];
#pragma unroll
            for (int u = 0; u < 6; ++u) v[u] = *(const uint4*)(base + (size_t)idx[u] * 128);
#pragma unroll
            for (int u = 0; u < 6; ++u) addv(acc, v[u]);
#pragma unroll
            for (int u = 0; u < 6; ++u) idx[u] = nxt[u];
        }
        uint4 v[6];
#pragma unroll
        for (int u = 0; u < 6; ++u) v[u] = *(const uint4*)(base + (size_t)idx[u] * 128);
#pragma unroll
        for (int u = 0; u < 6; ++u) addv(acc, v[u]);
        i = nb;
    }
    for (; i < n; ++i) {
        uint4 v = *(const uint4*)(base + (size_t)list[i] * 128);
        addv(acc, v);
    }

    float inv = 1.f / fmaxf((float)n, 1.f);
    __half h[8];
#pragma unroll
    for (int j = 0; j < 8; ++j) h[j] = __float2half(acc[j] * inv);
    *(uint4*)(out + g * 8) = *(uint4*)h;
}

// ---------------- prep: fp32 -> fp16 weights, summed root weights / biases, cursor init ----------------

__global__ __launch_bounds__(256) void prep_k(
    const float* __restrict__ wd,     const float* __restrict__ wc,     const float* __restrict__ m1w,
    const float* __restrict__ dd1_wl, const float* __restrict__ cd1_wl, const float* __restrict__ dc1_wl,
    const float* __restrict__ dc1_wr, const float* __restrict__ dd1_wr, const float* __restrict__ cd1_wr,
    const float* __restrict__ dd1_bl, const float* __restrict__ cd1_bl,
    const float* __restrict__ dd2_wl, const float* __restrict__ cd2_wl, const float* __restrict__ dc2_wl,
    const float* __restrict__ dc2_wr, const float* __restrict__ dd2_wr, const float* __restrict__ cd2_wr,
    const float* __restrict__ dd2_bl, const float* __restrict__ cd2_bl,
    f16* __restrict__ wd16, f16* __restrict__ wc16, f16* __restrict__ m1w16,
    f16* __restrict__ dd1_wl16, f16* __restrict__ cd1_wl16, f16* __restrict__ dc1_wl16,
    f16* __restrict__ dc1_wr16, f16* __restrict__ wr1s16,
    f16* __restrict__ dd2_wl16, f16* __restrict__ cd2_wl16, f16* __restrict__ dc2_wl16,
    f16* __restrict__ dc2_wr16, f16* __restrict__ wr2s16,
    float* __restrict__ bsum1, float* __restrict__ bsum2,
    int* __restrict__ bucket_cur)
{
    int i = blockIdx.x * 256 + threadIdx.x;
    if (i < 128 * 256) wd16[i] = (f16)wd[i];
    if (i < 128 * 512) wc16[i] = (f16)wc[i];
    if (i < 128 * 384) m1w16[i] = (f16)m1w[i];
    if (i < 128 * 128) {
        dd1_wl16[i] = (f16)dd1_wl[i];
        cd1_wl16[i] = (f16)cd1_wl[i];
        dc1_wl16[i] = (f16)dc1_wl[i];
        dc1_wr16[i] = (f16)dc1_wr[i];
        wr1s16[i]   = (f16)(dd1_wr[i] + cd1_wr[i]);
        dd2_wl16[i] = (f16)dd2_wl[i];
        cd2_wl16[i] = (f16)cd2_wl[i];
        dc2_wl16[i] = (f16)dc2_wl[i];
        dc2_wr16[i] = (f16)dc2_wr[i];
        wr2s16[i]   = (f16)(dd2_wr[i] + cd2_wr[i]);
    }
    if (i < 128) {
        bsum1[i] = dd1_bl[i] + cd1_bl[i];
        bsum2[i] = dd2_bl[i] + cd2_bl[i];
    }
    if (i < NBTOT) bucket_cur[i] = i * BCAP;
}

// ---------------- standalone 2-job GEMM wrapper (layers + head) ----------------

template<typename AT, int MODE>
__global__ __launch_bounds__(256) void mgemm_k(
    const AT* A00, const int* I00, const f16* W00, int K00, int S00,
    const AT* A01, const int* I01, const f16* W01, int K01, int S01,
    const AT* A02, const int* I02, const f16* W02, int K02, int S02,
    const float* bias0, f16* Ch0, int M0,
    const AT* A10, const int* I10, const f16* W10, int K10, int S10,
    const AT* A11, const int* I11, const f16* W11, int K11, int S11,
    const AT* A12, const int* I12, const f16* W12, int K12, int S12,
    const float* bias1, f16* Ch1, int M1,
    int split,
    const float* m2w, const float* m2b, float* Cf)
{
    __shared__ f16 As[128][72];
    __shared__ f16 Ws[128][72];
    const bool j1 = (int)blockIdx.x >= split;
    const int mb = ((int)blockIdx.x - (j1 ? split : 0)) * 128;
    if (!j1)
        gemm_core<AT, MODE>(As, Ws, mb, A00, I00, W00, K00, S00, A01, I01, W01, K01, S01,
                            A02, I02, W02, K02, S02, bias0, Ch0, M0, m2w, m2b, Cf);
    else
        gemm_core<AT, MODE>(As, Ws, mb, A10, I10, W10, K10, S10, A11, I11, W11, K11, S11,
                            A12, I12, W12, K12, S12, bias1, Ch1, M1, m2w, m2b, Cf);
}

// ---------------- launch ----------------

extern "C" void kernel_launch(void* const* d_in, const int* in_sizes, int n_in,
                              void* d_out, int out_size, void* d_ws, size_t ws_size,
                              hipStream_t stream)
{
    const float* x_drug = (const float*)d_in[0];
    const float* x_cell = (const float*)d_in[1];
    const int* ei_dd_src = (const int*)d_in[2];
    const int* ei_dd_dst = (const int*)d_in[3];
    const int* ei_dc_src = (const int*)d_in[4];
    const int* ei_dc_dst = (const int*)d_in[5];
    const int* ei_cd_src = (const int*)d_in[6];
    const int* ei_cd_dst = (const int*)d_in[7];
    const int* q_da = (const int*)d_in[8];
    const int* q_db = (const int*)d_in[9];
    const int* q_c  = (const int*)d_in[10];
    const float* wd = (const float*)d_in[11];
    const float* bd = (const float*)d_in[12];
    const float* wc = (const float*)d_in[13];
    const float* bc = (const float*)d_in[14];
    const float* dd1_wl = (const float*)d_in[15]; const float* dd1_bl = (const float*)d_in[16]; const float* dd1_wr = (const float*)d_in[17];
    const float* cd1_wl = (const float*)d_in[18]; const float* cd1_bl = (const float*)d_in[19]; const float* cd1_wr = (const float*)d_in[20];
    const float* dc1_wl = (const float*)d_in[21]; const float* dc1_bl = (const float*)d_in[22]; const float* dc1_wr = (const float*)d_in[23];
    const float* dd2_wl = (const float*)d_in[24]; const float* dd2_bl = (const float*)d_in[25]; const float* dd2_wr = (const float*)d_in[26];
    const float* cd2_wl = (const float*)d_in[27]; const float* cd2_bl = (const float*)d_in[28]; const float* cd2_wr = (const float*)d_in[29];
    const float* dc2_wl = (const float*)d_in[30]; const float* dc2_bl = (const float*)d_in[31]; const float* dc2_wr = (const float*)d_in[32];
    const float* m1_w = (const float*)d_in[33]; const float* m1_b = (const float*)d_in[34];
    const float* m2_w = (const float*)d_in[35]; const float* m2_b = (const float*)d_in[36];
    float* out = (float*)d_out;

    char* wsp = (char*)d_ws;
    size_t off = 0;
    auto alloc = [&](size_t bytes) -> void* {
        void* p = wsp + off;
        off += (bytes + 255) & ~(size_t)255;
        return p;
    };

    f16* xd32_16 = (f16*)alloc((size_t)NDRUG * 256 * 2);
    f16* xc32_16 = (f16*)alloc((size_t)NCELL * 512 * 2);

    __half* xd_h     = (__half*)alloc((size_t)NDRUG * 128 * 2);
    __half* xc_h     = (__half*)alloc((size_t)NCELL * 128 * 2);
    __half* hd_h     = (__half*)alloc((size_t)NDRUG * 128 * 2);
    __half* hc_h     = (__half*)alloc((size_t)NCELL * 128 * 2);
    __half* mean_a_h = (__half*)alloc((size_t)NDRUG * 128 * 2);
    __half* mean_b_h = (__half*)alloc((size_t)NDRUG * 128 * 2);
    __half* mean_c_h = (__half*)alloc((size_t)NCELL * 128 * 2);
    __half* od_h     = (__half*)alloc((size_t)NDRUG * 128 * 2);
    __half* oc_h     = (__half*)alloc((size_t)NCELL * 128 * 2);

    f16* wd16     = (f16*)alloc(128 * 256 * 2);
    f16* wc16     = (f16*)alloc(128 * 512 * 2);
    f16* m1w16    = (f16*)alloc(128 * 384 * 2);
    f16* dd1_wl16 = (f16*)alloc(128 * 128 * 2);
    f16* cd1_wl16 = (f16*)alloc(128 * 128 * 2);
    f16* dc1_wl16 = (f16*)alloc(128 * 128 * 2);
    f16* dc1_wr16 = (f16*)alloc(128 * 128 * 2);
    f16* wr1s16   = (f16*)alloc(128 * 128 * 2);
    f16* dd2_wl16 = (f16*)alloc(128 * 128 * 2);
    f16* cd2_wl16 = (f16*)alloc(128 * 128 * 2);
    f16* dc2_wl16 = (f16*)alloc(128 * 128 * 2);
    f16* dc2_wr16 = (f16*)alloc(128 * 128 * 2);
    f16* wr2s16   = (f16*)alloc(128 * 128 * 2);
    float* bsum1  = (float*)alloc(128 * 4);
    float* bsum2  = (float*)alloc(128 * 4);

    int* bucket_cur  = (int*)alloc((size_t)NBTOT * 4);
    int* rowptr      = (int*)alloc((size_t)NNODE * 4);
    int* cnt_arr     = (int*)alloc((size_t)NNODE * 4);
    unsigned* binned = (unsigned*)alloc((size_t)NBTOT * BCAP * 4);

    // 1) prep (weights->fp16, bucket cursor init)
    prep_k<<<256, 256, 0, stream>>>(
        wd, wc, m1_w,
        dd1_wl, cd1_wl, dc1_wl, dc1_wr, dd1_wr, cd1_wr, dd1_bl, cd1_bl,
        dd2_wl, cd2_wl, dc2_wl, dc2_wr, dd2_wr, cd2_wr, dd2_bl, cd2_bl,
        wd16, wc16, m1w16,
        dd1_wl16, cd1_wl16, dc1_wl16, dc1_wr16, wr1s16,
        dd2_wl16, cd2_wl16, dc2_wl16, dc2_wr16, wr2s16,
        bsum1, bsum2, bucket_cur);

    // 2) fused: binned scatter (8-deep ILP both passes) | fp32->fp16 input conversion
    scatter_cvt_k<<<NBLK + CVTG, 256, 0, stream>>>(
        ei_dd_src, ei_dd_dst, ei_cd_src, ei_cd_dst, ei_dc_src, ei_dc_dst,
        bucket_cur, binned, x_drug, xd32_16, x_cell, xc32_16);

    // 3) fused: per-bucket counting sort (in-place) | input projection GEMMs
    bucket_proj_k<<<NBTOT + GC_PROJ + GD_PROJ, 256, 0, stream>>>(
        binned, bucket_cur, rowptr, cnt_arr,
        xc32_16, wc16, bc, (f16*)xc_h,
        xd32_16, wd16, bd, (f16*)xd_h);

    const f16*   fnull = nullptr;
    const float* f32null = nullptr;
    const int*   inull = nullptr;
    const int GD = GD_PROJ;
    const int GC = GC_PROJ;
    const int GQ = (NQ + 127) / 128;

    const int AGG_GRID = (NNODE + 15) / 16;

    // 4) layer 1 aggregation
    agg_all_k<<<AGG_GRID, 256, 0, stream>>>(xd_h, xc_h, rowptr, cnt_arr, binned,
                                            mean_a_h, mean_b_h, mean_c_h);

    // 5) fused layer 1 GEMMs (cell first) -> fp16 h tables
    mgemm_k<f16, 1><<<GD + GC, 256, 0, stream>>>(
        (const f16*)mean_c_h, inull, dc1_wl16, 128, 128,
        (const f16*)xc_h,     inull, dc1_wr16, 128, 128,
        fnull,                inull, fnull,    0, 0,
        dc1_bl, (f16*)hc_h, NCELL,
        (const f16*)mean_a_h, inull, dd1_wl16, 128, 128,
        (const f16*)mean_b_h, inull, cd1_wl16, 128, 128,
        (const f16*)xd_h,     inull, wr1s16,   128, 128,
        bsum1, (f16*)hd_h, NDRUG,
        GC, f32null, f32null, nullptr);

    // 6) layer 2 aggregation
    agg_all_k<<<AGG_GRID, 256, 0, stream>>>(hd_h, hc_h, rowptr, cnt_arr, binned,
                                            mean_a_h, mean_b_h, mean_c_h);

    // 7) fused layer 2 GEMMs (cell first) -> fp16 od/oc
    mgemm_k<f16, 0><<<GD + GC, 256, 0, stream>>>(
        (const f16*)mean_c_h, inull, dc2_wl16, 128, 128,
        (const f16*)hc_h,     inull, dc2_wr16, 128, 128,
        fnull,                inull, fnull,    0, 0,
        dc2_bl, (f16*)oc_h, NCELL,
        (const f16*)mean_a_h, inull, dd2_wl16, 128, 128,
        (const f16*)mean_b_h, inull, cd2_wl16, 128, 128,
        (const f16*)hd_h,     inull, wr2s16,   128, 128,
        bsum2, (f16*)od_h, NDRUG,
        GC, f32null, f32null, nullptr);

    // 8) fused head: gather + [B,384]@[384,128]^T + relu + dot(m2_w) + m2_b
    mgemm_k<f16, 2><<<GQ, 256, 0, stream>>>(
        (const f16*)od_h, q_da, m1w16,       128, 384,
        (const f16*)od_h, q_db, m1w16 + 128, 128, 384,
        (const f16*)oc_h, q_c,  m1w16 + 256, 128, 384,
        m1_b, nullptr, NQ,
        fnull, inull, fnull, 0, 0,
        fnull, inull, fnull, 0, 0,
        fnull, inull, fnull, 0, 0,
        f32null, nullptr, 0,
        GQ, m2_w, m2_b, out);
}

// Round 14
// 435.142 us; speedup vs baseline: 1.1673x; 1.1673x over previous
//
#include <hip/hip_runtime.h>
#include <hip/hip_fp16.h>

typedef _Float16 f16;
typedef f16 f16x8 __attribute__((ext_vector_type(8)));
typedef float f32x4 __attribute__((ext_vector_type(4)));

#define NDRUG 100000
#define NCELL 20000
#define EDD   1600000
#define EDC   800000
#define ECD   800000
#define NQ    100000
#define ETOT  (EDD + ECD + EDC)
#define NNODE 220000              // unified dst space: [0,1e5) dd, [1e5,2e5) cd, [2e5,2.2e5) dc

// bucketed build: drug-dst space [0,200000) in 256-node buckets, cell-dst in 64-node buckets
#define NBD 782
#define NBC 313
#define NBTOT (NBD + NBC)          // 1095
#define ECHUNK 4096
#define NBLK ((ETOT + ECHUNK - 1) / ECHUNK)   // 782
#define BCAP 8192                  // fixed global capacity per bucket (mean 4096)
#define LCAP 6144                  // LDS sort capacity per bucket (mean 4096, +32 sigma)
#define CVTG 2048                  // grid-stride blocks for the cvt half of fused dispatch 1
#define GC_PROJ 157                // (NCELL+127)/128
#define GD_PROJ 782                // (NDRUG+127)/128

__device__ inline int bucket_of(int rdst) { return rdst < 200000 ? (rdst >> 8) : NBD + ((rdst - 200000) >> 6); }
__device__ inline int dl_of(int rdst)     { return rdst < 200000 ? (rdst & 255) : ((rdst - 200000) & 63); }

// ---------------- shared-memory layouts ----------------

struct GemmSh { f16 As[128][72]; f16 Ws[128][72]; };     // 36,864 B (+8 pad: 2-way alias free)
struct BktSh {
    int cnt[256]; int off[256]; int seg[256];
    unsigned short lrank[LCAP];
    unsigned srec[LCAP];
};                                                        // 39,936 B
union ShU { GemmSh g; BktSh b; };

// ---------------- GEMM core: C[M,128] = sum_s A_s @ W_s^T + bias ----------------
// 128x128 C-tile, 4 waves x 32 rows, BK=64, fp16 in, fp32 accum.
// MODE 0: fp16 store; MODE 1: relu+fp16 store; MODE 2: relu + dot(m2w) + m2b -> Cf[M].

template<typename AT, int MODE>
__device__ __forceinline__ void gemm_core(
    f16 (*As)[72], f16 (*Ws)[72], int mb,
    const AT* A0, const int* I0, const f16* W0, int K0, int S0,
    const AT* A1, const int* I1, const f16* W1, int K1, int S1,
    const AT* A2, const int* I2, const f16* W2, int K2, int S2,
    const float* bias, f16* Ch, int M,
    const float* m2w, const float* m2b, float* Cf)
{
    const int tid = threadIdx.x;
    const int w  = tid >> 6;
    const int l  = tid & 63;
    const int lc = l & 15;
    const int lq = l >> 4;
    const int sr = tid >> 1;
    const int sk = (tid & 1) * 32;

    f32x4 acc[2][8];
#pragma unroll
    for (int mi = 0; mi < 2; ++mi)
#pragma unroll
        for (int j = 0; j < 8; ++j) acc[mi][j] = (f32x4){0.f, 0.f, 0.f, 0.f};

    const AT*  Aseg[3] = {A0, A1, A2};
    const int* Iseg[3] = {I0, I1, I2};
    const f16* Wseg[3] = {W0, W1, W2};
    const int  Kseg[3] = {K0, K1, K2};
    const int  Sseg[3] = {S0, S1, S2};

    for (int s = 0; s < 3; ++s) {
        const AT* A = Aseg[s];
        if (!A) continue;
        const int* idx = Iseg[s];
        const f16* W = Wseg[s];
        const int K = Kseg[s], S = Sseg[s];

        int m = mb + sr; if (m >= M) m = M - 1;
        const AT*  arow = A + (size_t)(idx ? idx[m] : m) * (size_t)K;
        const f16* wrow = W + (size_t)sr * (size_t)S;

        for (int kt = 0; kt < K; kt += 64) {
            {
                const uint4* ap = (const uint4*)(arow + kt + sk);
                uint4 a0 = ap[0], a1 = ap[1], a2 = ap[2], a3 = ap[3];
                *(uint4*)&As[sr][sk]      = a0;
                *(uint4*)&As[sr][sk + 8]  = a1;
                *(uint4*)&As[sr][sk + 16] = a2;
                *(uint4*)&As[sr][sk + 24] = a3;
            }
            {
                const uint4* wp = (const uint4*)(wrow + kt + sk);
                uint4 w0 = wp[0], w1 = wp[1], w2 = wp[2], w3 = wp[3];
                *(uint4*)&Ws[sr][sk]      = w0;
                *(uint4*)&Ws[sr][sk + 8]  = w1;
                *(uint4*)&Ws[sr][sk + 16] = w2;
                *(uint4*)&Ws[sr][sk + 24] = w3;
            }
            __syncthreads();

#pragma unroll
            for (int ks = 0; ks < 64; ks += 32) {
                f16x8 a0 = *(const f16x8*)&As[32 * w + lc][ks + 8 * lq];
                f16x8 a1 = *(const f16x8*)&As[32 * w + 16 + lc][ks + 8 * lq];
#pragma unroll
                for (int j = 0; j < 8; ++j) {
                    f16x8 b = *(const f16x8*)&Ws[16 * j + lc][ks + 8 * lq];
                    acc[0][j] = __builtin_amdgcn_mfma_f32_16x16x32_f16(a0, b, acc[0][j], 0, 0, 0);
                    acc[1][j] = __builtin_amdgcn_mfma_f32_16x16x32_f16(a1, b, acc[1][j], 0, 0, 0);
                }
            }
            __syncthreads();
        }
    }

    // C/D layout: col = lc + 16j, row = 32w + 16mi + 4*lq + r
    if (MODE == 2) {
        float part[2][4];
#pragma unroll
        for (int mi = 0; mi < 2; ++mi)
#pragma unroll
            for (int r = 0; r < 4; ++r) part[mi][r] = 0.f;
#pragma unroll
        for (int j = 0; j < 8; ++j) {
            float bj = bias[16 * j + lc];
            float wv = m2w[16 * j + lc];
#pragma unroll
            for (int mi = 0; mi < 2; ++mi)
#pragma unroll
                for (int r = 0; r < 4; ++r) {
                    float v = acc[mi][j][r] + bj;
                    v = v > 0.f ? v : 0.f;
                    part[mi][r] = fmaf(v, wv, part[mi][r]);
                }
        }
#pragma unroll
        for (int mi = 0; mi < 2; ++mi)
#pragma unroll
            for (int r = 0; r < 4; ++r) {
                float p = part[mi][r];
#pragma unroll
                for (int o = 1; o < 16; o <<= 1) p += __shfl_xor(p, o, 16);
                if (lc == 0) {
                    int row = mb + 32 * w + 16 * mi + 4 * lq + r;
                    if (row < M) Cf[row] = p + m2b[0];
                }
            }
    } else {
#pragma unroll
        for (int j = 0; j < 8; ++j) {
            float bj = bias[16 * j + lc];
#pragma unroll
            for (int mi = 0; mi < 2; ++mi)
#pragma unroll
                for (int r = 0; r < 4; ++r) {
                    float v = acc[mi][j][r] + bj;
                    if (MODE == 1) v = v > 0.f ? v : 0.f;
                    int row = mb + 32 * w + 16 * mi + 4 * lq + r;
                    if (row < M) Ch[(size_t)row * 128 + 16 * j + lc] = (f16)v;
                }
        }
    }
}

// ---------------- fused dispatch 1: scatter (blocks < NBLK) | fp32->fp16 cvt ----------------

__device__ __forceinline__ int dst_decode(int e,
    const int* __restrict__ ddd, const int* __restrict__ cdd, const int* __restrict__ dcd)
{
    if (e < EDD) return ddd[e];
    if (e < EDD + ECD) return 100000 + cdd[e - EDD];
    return 200000 + dcd[e - EDD - ECD];
}

__device__ __forceinline__ void edge_decode(int e,
    const int* __restrict__ dds, const int* __restrict__ ddd,
    const int* __restrict__ cds, const int* __restrict__ cdd,
    const int* __restrict__ dcs, const int* __restrict__ dcd,
    int& src, int& rdst)
{
    if (e < EDD) { src = dds[e]; rdst = ddd[e]; }
    else if (e < EDD + ECD) { int i = e - EDD; src = cds[i]; rdst = 100000 + cdd[i]; }
    else { int i = e - EDD - ECD; src = dcs[i]; rdst = 200000 + dcd[i]; }
}

__global__ __launch_bounds__(256) void scatter_cvt_k(
    const int* __restrict__ dds, const int* __restrict__ ddd,
    const int* __restrict__ cds, const int* __restrict__ cdd,
    const int* __restrict__ dcs, const int* __restrict__ dcd,
    int* __restrict__ bucket_cur, unsigned* __restrict__ binned,
    const float* __restrict__ xd, f16* __restrict__ xd16,
    const float* __restrict__ xc, f16* __restrict__ xc16)
{
    __shared__ int lh[NBTOT];
    __shared__ int lbase[NBTOT];
    int tid = threadIdx.x;

    if ((int)blockIdx.x < NBLK) {
        for (int i = tid; i < NBTOT; i += 256) lh[i] = 0;
        __syncthreads();

        int base = blockIdx.x * ECHUNK;
        int end = base + ECHUNK; if (end > ETOT) end = ETOT;

        // pass A: bucket counts (dst only), 4-deep ILP
        int e = base + tid;
        for (; e + 768 < end; e += 1024) {
            int r0 = dst_decode(e,       ddd, cdd, dcd);
            int r1 = dst_decode(e + 256, ddd, cdd, dcd);
            int r2 = dst_decode(e + 512, ddd, cdd, dcd);
            int r3 = dst_decode(e + 768, ddd, cdd, dcd);
            atomicAdd(&lh[bucket_of(r0)], 1);
            atomicAdd(&lh[bucket_of(r1)], 1);
            atomicAdd(&lh[bucket_of(r2)], 1);
            atomicAdd(&lh[bucket_of(r3)], 1);
        }
        for (; e < end; e += 256)
            atomicAdd(&lh[bucket_of(dst_decode(e, ddd, cdd, dcd))], 1);
        __syncthreads();

        for (int i = tid; i < NBTOT; i += 256) {
            int c = lh[i];
            lbase[i] = c ? atomicAdd(&bucket_cur[i], c) : 0;
            lh[i] = 0;
        }
        __syncthreads();

        // pass B: rank + write packed records, 8-deep ILP
        e = base + tid;
        for (; e + 1792 < end; e += 2048) {
            int s[8], r[8], b[8], k[8];
#pragma unroll
            for (int u = 0; u < 8; ++u)
                edge_decode(e + 256 * u, dds, ddd, cds, cdd, dcs, dcd, s[u], r[u]);
#pragma unroll
            for (int u = 0; u < 8; ++u) b[u] = bucket_of(r[u]);
#pragma unroll
            for (int u = 0; u < 8; ++u) k[u] = atomicAdd(&lh[b[u]], 1);
#pragma unroll
            for (int u = 0; u < 8; ++u)
                binned[lbase[b[u]] + k[u]] = ((unsigned)dl_of(r[u]) << 17) | (unsigned)s[u];
        }
        for (; e < end; e += 256) {
            int s, r;
            edge_decode(e, dds, ddd, cds, cdd, dcs, dcd, s, r);
            int b = bucket_of(r);
            int k = atomicAdd(&lh[b], 1);
            binned[lbase[b] + k] = ((unsigned)dl_of(r) << 17) | (unsigned)s;
        }
    } else {
        // coalesced fp32->fp16 conversion, grid-stride over CVTG blocks
        const long TD = (long)NDRUG * 256 / 8;
        const long TC = (long)NCELL * 512 / 8;
        long stride = (long)CVTG * 256;
        for (long t = (long)((int)blockIdx.x - NBLK) * 256 + tid; t < TD + TC; t += stride) {
            const float* src; f16* dst; long p;
            if (t < TD) { src = xd; dst = xd16; p = t; }
            else        { src = xc; dst = xc16; p = t - TD; }
            const float4* sp = (const float4*)(src + p * 8);
            float4 u = sp[0], v = sp[1];
            f16x8 h;
            h[0] = (f16)u.x; h[1] = (f16)u.y; h[2] = (f16)u.z; h[3] = (f16)u.w;
            h[4] = (f16)v.x; h[5] = (f16)v.y; h[6] = (f16)v.z; h[7] = (f16)v.w;
            *(f16x8*)(dst + p * 8) = h;
        }
    }
}

// ---------------- fused dispatch 2: bucket counting-sort (blocks < NBTOT) | proj GEMM ----------------

__global__ __launch_bounds__(256) void bucket_proj_k(
    unsigned* __restrict__ binned, const int* __restrict__ bucket_cur,
    int* __restrict__ rowptr, int* __restrict__ cnt_arr,
    const f16* __restrict__ xc32_16, const f16* __restrict__ wc16, const float* __restrict__ bc, f16* __restrict__ xc_h,
    const f16* __restrict__ xd32_16, const f16* __restrict__ wd16, const float* __restrict__ bd, f16* __restrict__ xd_h)
{
    __shared__ ShU sh;
    int tid = threadIdx.x;

    if ((int)blockIdx.x < NBTOT) {
        int b = blockIdx.x;
        int gbase = b * BCAP;
        int n = bucket_cur[b] - gbase;
        n = n < 0 ? 0 : (n > LCAP ? LCAP : n);

        sh.b.cnt[tid] = 0;
        __syncthreads();
        for (int j = tid; j < n; j += 256) {
            unsigned r = binned[gbase + j];
            sh.b.lrank[j] = (unsigned short)atomicAdd(&sh.b.cnt[r >> 17], 1);
        }
        __syncthreads();
        int c = sh.b.cnt[tid];
        sh.b.seg[tid] = c; __syncthreads();
        for (int o = 1; o < 256; o <<= 1) {
            int v = (tid >= o) ? sh.b.seg[tid - o] : 0;
            __syncthreads();
            sh.b.seg[tid] += v;
            __syncthreads();
        }
        sh.b.off[tid] = sh.b.seg[tid] - c;
        __syncthreads();

        // rowptr + counts for every node in this bucket
        if (b < NBD) {
            int rdst = b * 256 + tid;
            if (rdst < 200000) { rowptr[rdst] = gbase + sh.b.off[tid]; cnt_arr[rdst] = c; }
        } else {
            if (tid < 64) {
                int node = (b - NBD) * 64 + tid;
                if (node < NCELL) { rowptr[200000 + node] = gbase + sh.b.off[tid]; cnt_arr[200000 + node] = c; }
            }
        }

        // node-sorted order in LDS (re-read is L2-hit)
        for (int j = tid; j < n; j += 256) {
            unsigned r = binned[gbase + j];
            int p = sh.b.off[r >> 17] + sh.b.lrank[j];
            sh.b.srec[p] = r & 0x1FFFF;
        }
        __syncthreads();

        // in-place linear write back (block owns this region exclusively)
        for (int p = tid; p < n; p += 256) binned[gbase + p] = sh.b.srec[p];
    } else {
        int bid = (int)blockIdx.x - NBTOT;
        const f16* fn = nullptr; const int* in_ = nullptr;
        if (bid < GC_PROJ) {
            gemm_core<f16, 0>(sh.g.As, sh.g.Ws, bid * 128,
                xc32_16, in_, wc16, 512, 512,
                fn, in_, fn, 0, 0,
                fn, in_, fn, 0, 0,
                bc, xc_h, NCELL, nullptr, nullptr, nullptr);
        } else {
            gemm_core<f16, 0>(sh.g.As, sh.g.Ws, (bid - GC_PROJ) * 128,
                xd32_16, in_, wd16, 256, 256,
                fn, in_, fn, 0, 0,
                fn, in_, fn, 0, 0,
                bd, xd_h, NDRUG, nullptr, nullptr, nullptr);
        }
    }
}

// ---------------- merged mean aggregation over bucket-padded CSR, fp16 rows ----------------

__device__ inline void addv(float* acc, uint4 v)
{
    const __half2* h = (const __half2*)&v;
#pragma unroll
    for (int j = 0; j < 4; ++j) {
        float2 f = __half22float2(h[j]);
        acc[2 * j]     += f.x;
        acc[2 * j + 1] += f.y;
    }
}

__global__ __launch_bounds__(256) void agg_all_k(
    const __half* __restrict__ t_d, const __half* __restrict__ t_c,
    const int* __restrict__ rowptr, const int* __restrict__ cnt_arr,
    const unsigned* __restrict__ packed,
    __half* __restrict__ m_a, __half* __restrict__ m_b, __half* __restrict__ m_c)
{
    int gid = blockIdx.x * 16 + (threadIdx.x >> 4);
    if (gid >= NNODE) return;
    int g = threadIdx.x & 15;

    const __half* tab; __half* out;
    if (gid < 100000)      { tab = t_d; out = m_a + (size_t)gid * 128; }
    else if (gid < 200000) { tab = t_c; out = m_b + (size_t)(gid - 100000) * 128; }
    else                   { tab = t_d; out = m_c + (size_t)(gid - 200000) * 128; }

    int s = rowptr[gid];
    int n = cnt_arr[gid];
    const unsigned* list = packed + s;
    const __half* base = tab + (size_t)g * 8;

    float acc[8];
#pragma unroll
    for (int j = 0; j < 8; ++j) acc[j] = 0.f;

    int i = 0;
    int nb = n & ~3;
    if (nb) {
        // software pipeline: prefetch next quad of list entries while rows load
        unsigned l0 = list[0], l1 = list[1], l2 = list[2], l3 = list[3];
        for (i = 4; i < nb; i += 4) {
            unsigned m0 = list[i], m1 = list[i + 1], m2 = list[i + 2], m3 = list[i + 3];
            uint4 v0 = *(const uint4*)(base + (size_t)l0 * 128);
            uint4 v1 = *(const uint4*)(base + (size_t)l1 * 128);
            uint4 v2 = *(const uint4*)(base + (size_t)l2 * 128);
            uint4 v3 = *(const uint4*)(base + (size_t)l3 * 128);
            addv(acc, v0); addv(acc, v1); addv(acc, v2); addv(acc, v3);
            l0 = m0; l1 = m1; l2 = m2; l3 = m3;
        }
        uint4 v0 = *(const uint4*)(base + (size_t)l0 * 128);
        uint4 v1 = *(const uint4*)(base + (size_t)l1 * 128);
        uint4 v2 = *(const uint4*)(base + (size_t)l2 * 128);
        uint4 v3 = *(const uint4*)(base + (size_t)l3 * 128);
        addv(acc, v0); addv(acc, v1); addv(acc, v2); addv(acc, v3);
        i = nb;
    }
    for (; i < n; ++i) {
        uint4 v = *(const uint4*)(base + (size_t)list[i] * 128);
        addv(acc, v);
    }

    float inv = 1.f / fmaxf((float)n, 1.f);
    __half h[8];
#pragma unroll
    for (int j = 0; j < 8; ++j) h[j] = __float2half(acc[j] * inv);
    *(uint4*)(out + g * 8) = *(uint4*)h;
}

// ---------------- prep: fp32 -> fp16 weights, summed root weights / biases, cursor init ----------------

__global__ __launch_bounds__(256) void prep_k(
    const float* __restrict__ wd,     const float* __restrict__ wc,     const float* __restrict__ m1w,
    const float* __restrict__ dd1_wl, const float* __restrict__ cd1_wl, const float* __restrict__ dc1_wl,
    const float* __restrict__ dc1_wr, const float* __restrict__ dd1_wr, const float* __restrict__ cd1_wr,
    const float* __restrict__ dd1_bl, const float* __restrict__ cd1_bl,
    const float* __restrict__ dd2_wl, const float* __restrict__ cd2_wl, const float* __restrict__ dc2_wl,
    const float* __restrict__ dc2_wr, const float* __restrict__ dd2_wr, const float* __restrict__ cd2_wr,
    const float* __restrict__ dd2_bl, const float* __restrict__ cd2_bl,
    f16* __restrict__ wd16, f16* __restrict__ wc16, f16* __restrict__ m1w16,
    f16* __restrict__ dd1_wl16, f16* __restrict__ cd1_wl16, f16* __restrict__ dc1_wl16,
    f16* __restrict__ dc1_wr16, f16* __restrict__ wr1s16,
    f16* __restrict__ dd2_wl16, f16* __restrict__ cd2_wl16, f16* __restrict__ dc2_wl16,
    f16* __restrict__ dc2_wr16, f16* __restrict__ wr2s16,
    float* __restrict__ bsum1, float* __restrict__ bsum2,
    int* __restrict__ bucket_cur)
{
    int i = blockIdx.x * 256 + threadIdx.x;
    if (i < 128 * 256) wd16[i] = (f16)wd[i];
    if (i < 128 * 512) wc16[i] = (f16)wc[i];
    if (i < 128 * 384) m1w16[i] = (f16)m1w[i];
    if (i < 128 * 128) {
        dd1_wl16[i] = (f16)dd1_wl[i];
        cd1_wl16[i] = (f16)cd1_wl[i];
        dc1_wl16[i] = (f16)dc1_wl[i];
        dc1_wr16[i] = (f16)dc1_wr[i];
        wr1s16[i]   = (f16)(dd1_wr[i] + cd1_wr[i]);
        dd2_wl16[i] = (f16)dd2_wl[i];
        cd2_wl16[i] = (f16)cd2_wl[i];
        dc2_wl16[i] = (f16)dc2_wl[i];
        dc2_wr16[i] = (f16)dc2_wr[i];
        wr2s16[i]   = (f16)(dd2_wr[i] + cd2_wr[i]);
    }
    if (i < 128) {
        bsum1[i] = dd1_bl[i] + cd1_bl[i];
        bsum2[i] = dd2_bl[i] + cd2_bl[i];
    }
    if (i < NBTOT) bucket_cur[i] = i * BCAP;
}

// ---------------- standalone 2-job GEMM wrapper (layers + head) ----------------

template<typename AT, int MODE>
__global__ __launch_bounds__(256) void mgemm_k(
    const AT* A00, const int* I00, const f16* W00, int K00, int S00,
    const AT* A01, const int* I01, const f16* W01, int K01, int S01,
    const AT* A02, const int* I02, const f16* W02, int K02, int S02,
    const float* bias0, f16* Ch0, int M0,
    const AT* A10, const int* I10, const f16* W10, int K10, int S10,
    const AT* A11, const int* I11, const f16* W11, int K11, int S11,
    const AT* A12, const int* I12, const f16* W12, int K12, int S12,
    const float* bias1, f16* Ch1, int M1,
    int split,
    const float* m2w, const float* m2b, float* Cf)
{
    __shared__ f16 As[128][72];
    __shared__ f16 Ws[128][72];
    const bool j1 = (int)blockIdx.x >= split;
    const int mb = ((int)blockIdx.x - (j1 ? split : 0)) * 128;
    if (!j1)
        gemm_core<AT, MODE>(As, Ws, mb, A00, I00, W00, K00, S00, A01, I01, W01, K01, S01,
                            A02, I02, W02, K02, S02, bias0, Ch0, M0, m2w, m2b, Cf);
    else
        gemm_core<AT, MODE>(As, Ws, mb, A10, I10, W10, K10, S10, A11, I11, W11, K11, S11,
                            A12, I12, W12, K12, S12, bias1, Ch1, M1, m2w, m2b, Cf);
}

// ---------------- launch ----------------

extern "C" void kernel_launch(void* const* d_in, const int* in_sizes, int n_in,
                              void* d_out, int out_size, void* d_ws, size_t ws_size,
                              hipStream_t stream)
{
    const float* x_drug = (const float*)d_in[0];
    const float* x_cell = (const float*)d_in[1];
    const int* ei_dd_src = (const int*)d_in[2];
    const int* ei_dd_dst = (const int*)d_in[3];
    const int* ei_dc_src = (const int*)d_in[4];
    const int* ei_dc_dst = (const int*)d_in[5];
    const int* ei_cd_src = (const int*)d_in[6];
    const int* ei_cd_dst = (const int*)d_in[7];
    const int* q_da = (const int*)d_in[8];
    const int* q_db = (const int*)d_in[9];
    const int* q_c  = (const int*)d_in[10];
    const float* wd = (const float*)d_in[11];
    const float* bd = (const float*)d_in[12];
    const float* wc = (const float*)d_in[13];
    const float* bc = (const float*)d_in[14];
    const float* dd1_wl = (const float*)d_in[15]; const float* dd1_bl = (const float*)d_in[16]; const float* dd1_wr = (const float*)d_in[17];
    const float* cd1_wl = (const float*)d_in[18]; const float* cd1_bl = (const float*)d_in[19]; const float* cd1_wr = (const float*)d_in[20];
    const float* dc1_wl = (const float*)d_in[21]; const float* dc1_bl = (const float*)d_in[22]; const float* dc1_wr = (const float*)d_in[23];
    const float* dd2_wl = (const float*)d_in[24]; const float* dd2_bl = (const float*)d_in[25]; const float* dd2_wr = (const float*)d_in[26];
    const float* cd2_wl = (const float*)d_in[27]; const float* cd2_bl = (const float*)d_in[28]; const float* cd2_wr = (const float*)d_in[29];
    const float* dc2_wl = (const float*)d_in[30]; const float* dc2_bl = (const float*)d_in[31]; const float* dc2_wr = (const float*)d_in[32];
    const float* m1_w = (const float*)d_in[33]; const float* m1_b = (const float*)d_in[34];
    const float* m2_w = (const float*)d_in[35]; const float* m2_b = (const float*)d_in[36];
    float* out = (float*)d_out;

    char* wsp = (char*)d_ws;
    size_t off = 0;
    auto alloc = [&](size_t bytes) -> void* {
        void* p = wsp + off;
        off += (bytes + 255) & ~(size_t)255;
        return p;
    };

    f16* xd32_16 = (f16*)alloc((size_t)NDRUG * 256 * 2);
    f16* xc32_16 = (f16*)alloc((size_t)NCELL * 512 * 2);

    __half* xd_h     = (__half*)alloc((size_t)NDRUG * 128 * 2);
    __half* xc_h     = (__half*)alloc((size_t)NCELL * 128 * 2);
    __half* hd_h     = (__half*)alloc((size_t)NDRUG * 128 * 2);
    __half* hc_h     = (__half*)alloc((size_t)NCELL * 128 * 2);
    __half* mean_a_h = (__half*)alloc((size_t)NDRUG * 128 * 2);
    __half* mean_b_h = (__half*)alloc((size_t)NDRUG * 128 * 2);
    __half* mean_c_h = (__half*)alloc((size_t)NCELL * 128 * 2);
    __half* od_h     = (__half*)alloc((size_t)NDRUG * 128 * 2);
    __half* oc_h     = (__half*)alloc((size_t)NCELL * 128 * 2);

    f16* wd16     = (f16*)alloc(128 * 256 * 2);
    f16* wc16     = (f16*)alloc(128 * 512 * 2);
    f16* m1w16    = (f16*)alloc(128 * 384 * 2);
    f16* dd1_wl16 = (f16*)alloc(128 * 128 * 2);
    f16* cd1_wl16 = (f16*)alloc(128 * 128 * 2);
    f16* dc1_wl16 = (f16*)alloc(128 * 128 * 2);
    f16* dc1_wr16 = (f16*)alloc(128 * 128 * 2);
    f16* wr1s16   = (f16*)alloc(128 * 128 * 2);
    f16* dd2_wl16 = (f16*)alloc(128 * 128 * 2);
    f16* cd2_wl16 = (f16*)alloc(128 * 128 * 2);
    f16* dc2_wl16 = (f16*)alloc(128 * 128 * 2);
    f16* dc2_wr16 = (f16*)alloc(128 * 128 * 2);
    f16* wr2s16   = (f16*)alloc(128 * 128 * 2);
    float* bsum1  = (float*)alloc(128 * 4);
    float* bsum2  = (float*)alloc(128 * 4);

    int* bucket_cur  = (int*)alloc((size_t)NBTOT * 4);
    int* rowptr      = (int*)alloc((size_t)NNODE * 4);
    int* cnt_arr     = (int*)alloc((size_t)NNODE * 4);
    unsigned* binned = (unsigned*)alloc((size_t)NBTOT * BCAP * 4);

    // 1) prep (weights->fp16, bucket cursor init)
    prep_k<<<256, 256, 0, stream>>>(
        wd, wc, m1_w,
        dd1_wl, cd1_wl, dc1_wl, dc1_wr, dd1_wr, cd1_wr, dd1_bl, cd1_bl,
        dd2_wl, cd2_wl, dc2_wl, dc2_wr, dd2_wr, cd2_wr, dd2_bl, cd2_bl,
        wd16, wc16, m1w16,
        dd1_wl16, cd1_wl16, dc1_wl16, dc1_wr16, wr1s16,
        dd2_wl16, cd2_wl16, dc2_wl16, dc2_wr16, wr2s16,
        bsum1, bsum2, bucket_cur);

    // 2) fused: binned scatter (8-deep ILP, 782 blocks) | fp32->fp16 input conversion
    scatter_cvt_k<<<NBLK + CVTG, 256, 0, stream>>>(
        ei_dd_src, ei_dd_dst, ei_cd_src, ei_cd_dst, ei_dc_src, ei_dc_dst,
        bucket_cur, binned, x_drug, xd32_16, x_cell, xc32_16);

    // 3) fused: per-bucket counting sort (in-place) | input projection GEMMs
    bucket_proj_k<<<NBTOT + GC_PROJ + GD_PROJ, 256, 0, stream>>>(
        binned, bucket_cur, rowptr, cnt_arr,
        xc32_16, wc16, bc, (f16*)xc_h,
        xd32_16, wd16, bd, (f16*)xd_h);

    const f16*   fnull = nullptr;
    const float* f32null = nullptr;
    const int*   inull = nullptr;
    const int GD = GD_PROJ;
    const int GC = GC_PROJ;
    const int GQ = (NQ + 127) / 128;

    const int AGG_GRID = (NNODE + 15) / 16;

    // 4) layer 1 aggregation
    agg_all_k<<<AGG_GRID, 256, 0, stream>>>(xd_h, xc_h, rowptr, cnt_arr, binned,
                                            mean_a_h, mean_b_h, mean_c_h);

    // 5) fused layer 1 GEMMs (cell first) -> fp16 h tables
    mgemm_k<f16, 1><<<GD + GC, 256, 0, stream>>>(
        (const f16*)mean_c_h, inull, dc1_wl16, 128, 128,
        (const f16*)xc_h,     inull, dc1_wr16, 128, 128,
        fnull,                inull, fnull,    0, 0,
        dc1_bl, (f16*)hc_h, NCELL,
        (const f16*)mean_a_h, inull, dd1_wl16, 128, 128,
        (const f16*)mean_b_h, inull, cd1_wl16, 128, 128,
        (const f16*)xd_h,     inull, wr1s16,   128, 128,
        bsum1, (f16*)hd_h, NDRUG,
        GC, f32null, f32null, nullptr);

    // 6) layer 2 aggregation
    agg_all_k<<<AGG_GRID, 256, 0, stream>>>(hd_h, hc_h, rowptr, cnt_arr, binned,
                                            mean_a_h, mean_b_h, mean_c_h);

    // 7) fused layer 2 GEMMs (cell first) -> fp16 od/oc
    mgemm_k<f16, 0><<<GD + GC, 256, 0, stream>>>(
        (const f16*)mean_c_h, inull, dc2_wl16, 128, 128,
        (const f16*)hc_h,     inull, dc2_wr16, 128, 128,
        fnull,                inull, fnull,    0, 0,
        dc2_bl, (f16*)oc_h, NCELL,
        (const f16*)mean_a_h, inull, dd2_wl16, 128, 128,
        (const f16*)mean_b_h, inull, cd2_wl16, 128, 128,
        (const f16*)hd_h,     inull, wr2s16,   128, 128,
        bsum2, (f16*)od_h, NDRUG,
        GC, f32null, f32null, nullptr);

    // 8) fused head: gather + [B,384]@[384,128]^T + relu + dot(m2_w) + m2_b
    mgemm_k<f16, 2><<<GQ, 256, 0, stream>>>(
        (const f16*)od_h, q_da, m1w16,       128, 384,
        (const f16*)od_h, q_db, m1w16 + 128, 128, 384,
        (const f16*)oc_h, q_c,  m1w16 + 256, 128, 384,
        m1_b, nullptr, NQ,
        fnull, inull, fnull, 0, 0,
        fnull, inull, fnull, 0, 0,
        fnull, inull, fnull, 0, 0,
        f32null, nullptr, 0,
        GQ, m2_w, m2_b, out);
}